// Round 5
// baseline (789.108 us; speedup 1.0000x reference)
//
#include <hip/hip_runtime.h>
#include <hip/hip_bf16.h>
#include <stdint.h>

typedef _Float16 half8 __attribute__((ext_vector_type(8)));
typedef _Float16 half4v __attribute__((ext_vector_type(4)));
typedef float f32x4 __attribute__((ext_vector_type(4)));

#define T_STEPS 20
#define B_SZ 512
#define D_IN 4096
#define H_SZ 1024
#define C_SZ 100
#define M_TOT (T_STEPS * B_SZ)  // 10240
#define BK 32
#define KITERS (D_IN / BK)  // 128

// ---------- helpers ----------
__device__ __forceinline__ void gload16(const _Float16* g, _Float16* l) {
  __builtin_amdgcn_global_load_lds(
      (const __attribute__((address_space(1))) void*)g,
      (__attribute__((address_space(3))) void*)l, 16, 0, 0);
}

// two float4 (8 fp32) -> half8 hi + half8 lo residual
struct HL {
  half8 h;
  half8 l;
};
__device__ __forceinline__ HL split8(float4 a, float4 b) {
  HL r;
  auto p0 = __builtin_amdgcn_cvt_pkrtz(a.x, a.y);
  auto p1 = __builtin_amdgcn_cvt_pkrtz(a.z, a.w);
  auto p2 = __builtin_amdgcn_cvt_pkrtz(b.x, b.y);
  auto p3 = __builtin_amdgcn_cvt_pkrtz(b.z, b.w);
  r.h[0] = p0.x; r.h[1] = p0.y; r.h[2] = p1.x; r.h[3] = p1.y;
  r.h[4] = p2.x; r.h[5] = p2.y; r.h[6] = p3.x; r.h[7] = p3.y;
  auto q0 = __builtin_amdgcn_cvt_pkrtz(a.x - (float)p0.x, a.y - (float)p0.y);
  auto q1 = __builtin_amdgcn_cvt_pkrtz(a.z - (float)p1.x, a.w - (float)p1.y);
  auto q2 = __builtin_amdgcn_cvt_pkrtz(b.x - (float)p2.x, b.y - (float)p2.y);
  auto q3 = __builtin_amdgcn_cvt_pkrtz(b.z - (float)p3.x, b.w - (float)p3.y);
  r.l[0] = q0.x; r.l[1] = q0.y; r.l[2] = q1.x; r.l[3] = q1.y;
  r.l[4] = q2.x; r.l[5] = q2.y; r.l[6] = q3.x; r.l[7] = q3.y;
  return r;
}

// ---------- prep: fp32 -> (hi,lo) fp16 split (W1 only) ----------
__global__ void k_split4(const float* __restrict__ x, _Float16* __restrict__ hi,
                         _Float16* __restrict__ lo) {
  int64_t i = (int64_t)blockIdx.x * blockDim.x + threadIdx.x;
  float4 v = ((const float4* __restrict__)x)[i];
  half4v h, l;
  h.x = (_Float16)v.x; l.x = (_Float16)(v.x - (float)h.x);
  h.y = (_Float16)v.y; l.y = (_Float16)(v.y - (float)h.y);
  h.z = (_Float16)v.z; l.z = (_Float16)(v.z - (float)h.z);
  h.w = (_Float16)v.w; l.w = (_Float16)(v.w - (float)h.w);
  ((half4v*)hi)[i] = h;
  ((half4v*)lo)[i] = l;
}

// W2 [100][1024] -> padded [112][1024] hi/lo (pad rows zero)
__global__ void k_prep_w2(const float* __restrict__ w2, _Float16* __restrict__ hi,
                          _Float16* __restrict__ lo) {
  int i = blockIdx.x * 256 + threadIdx.x;
  float v = (i < C_SZ * H_SZ) ? w2[i] : 0.0f;
  _Float16 h = (_Float16)v;
  hi[i] = h;
  lo[i] = (_Float16)(v - (float)h);
}

// ---------- big GEMM: Hbuf[M_TOT][H_SZ] = Z * W1^T, 3-term fp16 split ----------
// R4 post-mortem: conflicts 0, FETCH ideal, but barrier placement exposed full
// load latency (b2 right after glds issue; z prefetch drained one short MFMA
// phase after issue) -> MfmaUtil 27%, 411 us. R5: issue ALL loads for tile i+1
// right after b2 so the whole MFMA phase of tile i sits between issue and the
// draining barrier (next b1). W double-buffered (glds target), A single-buffered
// (reg round-trip + split). LDS 48 KB -> 3 blocks/CU, grid 640 fits one round.
__global__ __launch_bounds__(256) void k_gemm1(
    const float* __restrict__ Z,
    const _Float16* __restrict__ Whi, const _Float16* __restrict__ Wlo,
    float* __restrict__ Hbuf) {
  __shared__ _Float16 sAh[4096];
  __shared__ _Float16 sAl[4096];
  __shared__ _Float16 sWh[8192];  // 2 buffers
  __shared__ _Float16 sWl[8192];

  const int tid = threadIdx.x;
  const int lane = tid & 63;
  const int w = tid >> 6;

  const int bid = blockIdx.x;          // 0..639
  const int xcd = bid & 7;
  const int q = bid >> 3;
  const int mt = xcd * 10 + (q >> 3);
  const int nt = q & 7;
  const int64_t m0 = (int64_t)mt * 128;
  const int64_t n0 = (int64_t)nt * 128;

  // ---- A staging map (fused split): fragment order, wave w covers frag-block w (pass0)
  const int sfr = tid & 15;            // row within frag-block
  const int sq = (tid >> 4) & 3;       // k-quad
  const float* gz = Z + (m0 + (int64_t)(w * 16 + sfr)) * D_IN + sq * 8;
  const int aws = w * 512 + (sq * 16 + sfr) * 8;  // pass0 LDS f16 idx
  // pass1: +2048 LDS, +64*D_IN global

  // ---- W staging map (global_load_lds, fragment order, lane-linear dest)
  const _Float16* gW = Whi + (n0 + (int64_t)(w * 16 + (lane & 15))) * D_IN + (lane >> 4) * 8;
  const _Float16* gWl2 = Wlo + (n0 + (int64_t)(w * 16 + (lane & 15))) * D_IN + (lane >> 4) * 8;
  const int wws = w * 512 + lane * 8;  // within-buffer idx; +2048 second issue
  const int64_t g2w = (int64_t)64 * D_IN;

  // ---- frag read bases
  const int wm = (w >> 1) * 64;
  const int wn = (w & 1) * 64;
  const int ra = (wm >> 4) * 512 + lane * 8;
  const int rb = (wn >> 4) * 512 + lane * 8;
  const int fr = lane & 15;
  const int quad = lane >> 4;

  f32x4 acc[4][4] = {};

  // ---- prologue: issue tile-0 W glds (buffer 0) + z regs
  gload16(gW, &sWh[wws]);
  gload16(gW + g2w, &sWh[wws + 2048]);
  gload16(gWl2, &sWl[wws]);
  gload16(gWl2 + g2w, &sWl[wws + 2048]);
  float4 r00 = *(const float4*)(gz);
  float4 r01 = *(const float4*)(gz + 4);
  float4 r10 = *(const float4*)(gz + g2w);
  float4 r11 = *(const float4*)(gz + g2w + 4);

  for (int i = 0; i < KITERS; ++i) {
    __syncthreads();  // b1: drains W[i] glds + z[i] reg loads; prior A reads done

    // A: cvt hi/lo + fragment-ordered ds_write (conflict-free phases)
    {
      HL p0 = split8(r00, r01);
      *(half8*)&sAh[aws] = p0.h;
      *(half8*)&sAl[aws] = p0.l;
      HL p1 = split8(r10, r11);
      *(half8*)&sAh[aws + 2048] = p1.h;
      *(half8*)&sAl[aws + 2048] = p1.l;
    }

    __syncthreads();  // b2: A visible (lgkm only; vmcnt already drained)

    // issue ALL of tile i+1's loads now -> drained at next b1, hidden by MFMA
    const int woff = ((i + 1) & 1) * 4096;
    if (i + 1 < KITERS) {
      const int kt = (i + 1) * BK;
      gload16(gW + kt, &sWh[woff + wws]);
      gload16(gW + kt + g2w, &sWh[woff + wws + 2048]);
      gload16(gWl2 + kt, &sWl[woff + wws]);
      gload16(gWl2 + kt + g2w, &sWl[woff + wws + 2048]);
      r00 = *(const float4*)(gz + kt);
      r01 = *(const float4*)(gz + kt + 4);
      r10 = *(const float4*)(gz + kt + g2w);
      r11 = *(const float4*)(gz + kt + g2w + 4);
    }

    // MFMA phase on tile i (A in sA*, W in buffer i&1)
    const int wcur = (i & 1) * 4096;
    half8 ah[4], al[4], bh[4], bl[4];
#pragma unroll
    for (int j = 0; j < 4; ++j) {
      ah[j] = *(const half8*)&sAh[ra + j * 512];
      al[j] = *(const half8*)&sAl[ra + j * 512];
      bh[j] = *(const half8*)&sWh[wcur + rb + j * 512];
      bl[j] = *(const half8*)&sWl[wcur + rb + j * 512];
    }
#pragma unroll
    for (int a = 0; a < 4; ++a) {
#pragma unroll
      for (int b = 0; b < 4; ++b) {
        acc[a][b] = __builtin_amdgcn_mfma_f32_16x16x32_f16(ah[a], bh[b], acc[a][b], 0, 0, 0);
        acc[a][b] = __builtin_amdgcn_mfma_f32_16x16x32_f16(ah[a], bl[b], acc[a][b], 0, 0, 0);
        acc[a][b] = __builtin_amdgcn_mfma_f32_16x16x32_f16(al[a], bh[b], acc[a][b], 0, 0, 0);
      }
    }
  }

  // epilogue: C/D layout col=lane&15, row=quad*4+reg
#pragma unroll
  for (int a = 0; a < 4; ++a) {
#pragma unroll
    for (int r = 0; r < 4; ++r) {
      const int64_t row = m0 + wm + a * 16 + quad * 4 + r;
      float* dst = Hbuf + row * H_SZ + n0 + wn + fr;
#pragma unroll
      for (int b = 0; b < 4; ++b) dst[b * 16] = acc[a][b][r];
    }
  }
}

// ---------- BN stats: 64-wide coalesced column sums ----------
// block: 256 thr = 4 waves; wave covers 64 consecutive h (256 B coalesced),
// ty-group sums 128 rows; LDS reduce across 4 groups.
__global__ void k_stats(const float* __restrict__ Hbuf, const float* __restrict__ gamma,
                        float* __restrict__ scale, float* __restrict__ shift) {
  const int t = blockIdx.y;
  const int tx = threadIdx.x & 63;
  const int ty = threadIdx.x >> 6;  // 0..3
  const int h = blockIdx.x * 64 + tx;
  const float* p = Hbuf + ((int64_t)t * B_SZ + ty * 128) * H_SZ + h;
  float s = 0.f, s2 = 0.f;
#pragma unroll 8
  for (int i = 0; i < 128; ++i) {
    float v = p[(int64_t)i * H_SZ];
    s += v;
    s2 += v * v;
  }
  __shared__ float ss[4][64];
  __shared__ float sq[4][64];
  ss[ty][tx] = s;
  sq[ty][tx] = s2;
  __syncthreads();
  if (ty == 0) {
    float a = ss[0][tx] + ss[1][tx] + ss[2][tx] + ss[3][tx];
    float b = sq[0][tx] + sq[1][tx] + sq[2][tx] + sq[3][tx];
    const float mean = a * (1.0f / B_SZ);
    const float var = b * (1.0f / B_SZ) - mean * mean;
    const float rs = rsqrtf(var + 1e-4f);
    const float sc = gamma[t * H_SZ + h] * rs;
    scale[t * H_SZ + h] = sc;
    shift[t * H_SZ + h] = -mean * sc;
  }
}

// ---------- LIF recurrence per (b,h): spike count S ----------
__global__ void k_recur(const float* __restrict__ Hbuf, const float* __restrict__ scale,
                        const float* __restrict__ shift, _Float16* __restrict__ S) {
  const int idx = blockIdx.x * 256 + threadIdx.x;
  const int b = idx >> 10;
  const int h = idx & 1023;
  float mem = 0.f;
  int cnt = 0;
#pragma unroll
  for (int t = 0; t < T_STEPS; ++t) {
    float v = Hbuf[((int64_t)(t * B_SZ + b) << 10) + h];
    v = v * scale[(t << 10) + h] + shift[(t << 10) + h];
    mem = 0.95f * mem + v;
    if (mem - 1.0f > 0.0f) {
      ++cnt;
      mem -= 1.0f;
    }
  }
  S[idx] = (_Float16)cnt;
}

// ---------- GEMM2: out = S @ W2^T / 20, 2-term fp16 split (exact: S integer) ----------
__global__ void k_gemm2(const _Float16* __restrict__ S, const _Float16* __restrict__ W2h,
                        const _Float16* __restrict__ W2l, float* __restrict__ out) {
  const int wid = threadIdx.x >> 6;
  const int lane = threadIdx.x & 63;
  const int m0 = blockIdx.y * 64 + wid * 16;
  const int n0 = blockIdx.x * 16;
  const int fr = lane & 15;
  const int quad = lane >> 4;

  const _Float16* sp = S + (int64_t)(m0 + fr) * H_SZ + quad * 8;
  const _Float16* wph = W2h + (int64_t)(n0 + fr) * H_SZ + quad * 8;
  const _Float16* wpl = W2l + (int64_t)(n0 + fr) * H_SZ + quad * 8;

  f32x4 acc = {0.f, 0.f, 0.f, 0.f};
#pragma unroll 4
  for (int k = 0; k < H_SZ; k += 32) {
    half8 a = *(const half8*)(sp + k);
    half8 bh = *(const half8*)(wph + k);
    half8 bl = *(const half8*)(wpl + k);
    acc = __builtin_amdgcn_mfma_f32_16x16x32_f16(a, bh, acc, 0, 0, 0);
    acc = __builtin_amdgcn_mfma_f32_16x16x32_f16(a, bl, acc, 0, 0, 0);
  }
  const int col = n0 + fr;
  if (col < C_SZ) {
#pragma unroll
    for (int r = 0; r < 4; ++r) {
      const int row = m0 + quad * 4 + r;
      out[row * C_SZ + col] = acc[r] * (1.0f / T_STEPS);
    }
  }
}

extern "C" void kernel_launch(void* const* d_in, const int* in_sizes, int n_in,
                              void* d_out, int out_size, void* d_ws, size_t ws_size,
                              hipStream_t stream) {
  const float* z = (const float*)d_in[0];      // [20,512,4096]
  const float* W1 = (const float*)d_in[1];     // [1024,4096]
  const float* gamma = (const float*)d_in[2];  // [20,1024]
  const float* W2 = (const float*)d_in[3];     // [100,1024]
  float* out = (float*)d_out;                  // [512,100]

  char* ws = (char*)d_ws;
  size_t off = 0;
  auto alloc = [&](size_t bytes) -> void* {
    void* p = ws + off;
    off += (bytes + 255) & ~(size_t)255;
    return p;
  };
  _Float16* Whi = (_Float16*)alloc((size_t)H_SZ * D_IN * 2);
  _Float16* Wlo = (_Float16*)alloc((size_t)H_SZ * D_IN * 2);
  float* Hbuf = (float*)alloc((size_t)M_TOT * H_SZ * 4);
  float* scale = (float*)alloc((size_t)T_STEPS * H_SZ * 4);
  float* shift = (float*)alloc((size_t)T_STEPS * H_SZ * 4);
  _Float16* S = (_Float16*)alloc((size_t)B_SZ * H_SZ * 2);
  _Float16* W2h = (_Float16*)alloc((size_t)112 * H_SZ * 2);
  _Float16* W2l = (_Float16*)alloc((size_t)112 * H_SZ * 2);

  // 1) split W1 / W2 into fp16 hi/lo planes
  k_split4<<<(H_SZ * D_IN) / 1024, 256, 0, stream>>>(W1, Whi, Wlo);
  k_prep_w2<<<(112 * H_SZ) / 256, 256, 0, stream>>>(W2, W2h, W2l);

  // 2) batched fc1 GEMM, software-pipelined, XCD swizzle
  k_gemm1<<<640, 256, 0, stream>>>(z, Whi, Wlo, Hbuf);

  // 3) BN stats
  dim3 gs(H_SZ / 64, T_STEPS);  // (16, 20)
  k_stats<<<gs, 256, 0, stream>>>(Hbuf, gamma, scale, shift);

  // 4) LIF recurrence -> spike counts
  k_recur<<<(B_SZ * H_SZ) / 256, 256, 0, stream>>>(Hbuf, scale, shift, S);

  // 5) spike-count GEMM -> output
  dim3 g2(7, 8);
  k_gemm2<<<g2, 256, 0, stream>>>(S, W2h, W2l, out);
}

// Round 6
// 548.941 us; speedup vs baseline: 1.4375x; 1.4375x over previous
//
#include <hip/hip_runtime.h>
#include <hip/hip_bf16.h>
#include <stdint.h>

typedef _Float16 half8 __attribute__((ext_vector_type(8)));
typedef float f32x4 __attribute__((ext_vector_type(4)));

#define T_STEPS 20
#define B_SZ 512
#define D_IN 4096
#define H_SZ 1024
#define C_SZ 100
#define M_TOT (T_STEPS * B_SZ)  // 10240
#define BK 32
#define KITERS (D_IN / BK)  // 128

// ---------- helpers ----------
__device__ __forceinline__ void gload16(const _Float16* g, _Float16* l) {
  __builtin_amdgcn_global_load_lds(
      (const __attribute__((address_space(1))) void*)g,
      (__attribute__((address_space(3))) void*)l, 16, 0, 0);
}

// 8 fp32 -> half8 hi + half8 lo residual
struct HL {
  half8 h;
  half8 l;
};
__device__ __forceinline__ HL split8(float4 a, float4 b) {
  HL r;
  auto p0 = __builtin_amdgcn_cvt_pkrtz(a.x, a.y);
  auto p1 = __builtin_amdgcn_cvt_pkrtz(a.z, a.w);
  auto p2 = __builtin_amdgcn_cvt_pkrtz(b.x, b.y);
  auto p3 = __builtin_amdgcn_cvt_pkrtz(b.z, b.w);
  r.h[0] = p0.x; r.h[1] = p0.y; r.h[2] = p1.x; r.h[3] = p1.y;
  r.h[4] = p2.x; r.h[5] = p2.y; r.h[6] = p3.x; r.h[7] = p3.y;
  auto q0 = __builtin_amdgcn_cvt_pkrtz(a.x - (float)p0.x, a.y - (float)p0.y);
  auto q1 = __builtin_amdgcn_cvt_pkrtz(a.z - (float)p1.x, a.w - (float)p1.y);
  auto q2 = __builtin_amdgcn_cvt_pkrtz(b.x - (float)p2.x, b.y - (float)p2.y);
  auto q3 = __builtin_amdgcn_cvt_pkrtz(b.z - (float)p3.x, b.w - (float)p3.y);
  r.l[0] = q0.x; r.l[1] = q0.y; r.l[2] = q1.x; r.l[3] = q1.y;
  r.l[4] = q2.x; r.l[5] = q2.y; r.l[6] = q3.x; r.l[7] = q3.y;
  return r;
}

// ---------- prep: fp32 row-major -> fp16 hi/lo planes in FRAGMENT-TILE order ----
// Element (row=rt*128 + fb*16 + r, k=ki*32 + q*8 + k7) stored at
//   dst[((rt*128 + ki)*8 + fb)*512 + (q*16 + r)*8 + k7].
// gemm1's glds then reads lane-linear-contiguous 1 KiB per wave-issue and the
// LDS image is directly in MFMA fragment order -> frag reads are base+lane*16B,
// zero bank conflicts (R2 evidence: 2.1e7 conflicts from row-major LDS tiles).
// grid: (128 ki, 80 z-rowtiles + 8 W1-rowtiles), 256 thr; writes fully linear.
__global__ void k_prep_frag(const float* __restrict__ Z, _Float16* __restrict__ Azh,
                            _Float16* __restrict__ Azl, const float* __restrict__ W1,
                            _Float16* __restrict__ Wfh, _Float16* __restrict__ Wfl) {
  const int ki = blockIdx.x;
  int rt = blockIdx.y;
  const float* src;
  _Float16 *dh, *dl;
  if (rt < 80) {
    src = Z; dh = Azh; dl = Azl;
  } else {
    rt -= 80; src = W1; dh = Wfh; dl = Wfl;
  }
  const int t = threadIdx.x;
#pragma unroll
  for (int p = 0; p < 2; ++p) {
    const int o = t + p * 256;       // octet index 0..511
    const int fb = o >> 6;           // frag-block 0..7
    const int j = o & 63;            // (q*16 + r)
    const int q = j >> 4;
    const int r = j & 15;
    const float* s = src + (int64_t)(rt * 128 + fb * 16 + r) * D_IN + ki * 32 + q * 8;
    float4 a = *(const float4*)s;
    float4 b = *(const float4*)(s + 4);
    HL hl = split8(a, b);
    const int64_t d = (((int64_t)rt * 128 + ki) * 8 + fb) * 512 + j * 8;
    *(half8*)&dh[d] = hl.h;
    *(half8*)&dl[d] = hl.l;
  }
}

// W2 [100][1024] -> padded [112][1024] hi/lo (pad rows zero)
__global__ void k_prep_w2(const float* __restrict__ w2, _Float16* __restrict__ hi,
                          _Float16* __restrict__ lo) {
  int i = blockIdx.x * 256 + threadIdx.x;
  float v = (i < C_SZ * H_SZ) ? w2[i] : 0.0f;
  _Float16 h = (_Float16)v;
  hi[i] = h;
  lo[i] = (_Float16)(v - (float)h);
}

// ---------- big GEMM: Hbuf = Z * W1^T, 3-term fp16 split ----------
// R2/m97 structure EXACTLY (R4 reg-roundtrip staging: 411 us; R5 pipelining:
// 605 us; R2 pure-glds: 283 us with conflicts — this is R2 minus conflicts).
// Single-buffered 32 KB LDS, b1 -> 8 glds -> b2 -> ds_read frags -> 48 MFMA.
// Inputs pre-arranged in fragment-tile order: glds src is contiguous per wave,
// LDS lands in fragment order, frag reads conflict-free.
__global__ __launch_bounds__(256) void k_gemm1(
    const _Float16* __restrict__ Ahi, const _Float16* __restrict__ Alo,
    const _Float16* __restrict__ Whi, const _Float16* __restrict__ Wlo,
    float* __restrict__ Hbuf) {
  __shared__ _Float16 sAh[4096];
  __shared__ _Float16 sAl[4096];
  __shared__ _Float16 sWh[4096];
  __shared__ _Float16 sWl[4096];

  const int tid = threadIdx.x;
  const int lane = tid & 63;
  const int w = tid >> 6;

  const int bid = blockIdx.x;          // 0..639, XCD-band swizzle (R2: FETCH 957->185 MB)
  const int xcd = bid & 7;
  const int q = bid >> 3;
  const int mt = xcd * 10 + (q >> 3);
  const int nt = q & 7;

  // staging: wave w stages frag-blocks w and w+4; src contiguous 1 KiB/issue
  const int ls = w * 512 + lane * 8;   // LDS f16 idx (wave-uniform + lane*16B)
  const _Float16* gAh = Ahi + (int64_t)mt * (128 * 4096) + ls;
  const _Float16* gAl = Alo + (int64_t)mt * (128 * 4096) + ls;
  const _Float16* gWh = Whi + (int64_t)nt * (128 * 4096) + ls;
  const _Float16* gWl = Wlo + (int64_t)nt * (128 * 4096) + ls;

  // frag read bases (conflict-free: lane*16B linear)
  const int wm = (w >> 1) * 64;
  const int wn = (w & 1) * 64;
  const int ra = (wm >> 4) * 512 + lane * 8;
  const int rb = (wn >> 4) * 512 + lane * 8;
  const int fr = lane & 15;
  const int quad = lane >> 4;

  f32x4 acc[4][4] = {};

  for (int ki = 0; ki < KITERS; ++ki) {
    const int64_t so = (int64_t)ki * 4096;
    __syncthreads();
    gload16(gAh + so, &sAh[ls]);
    gload16(gAh + so + 2048, &sAh[ls + 2048]);
    gload16(gAl + so, &sAl[ls]);
    gload16(gAl + so + 2048, &sAl[ls + 2048]);
    gload16(gWh + so, &sWh[ls]);
    gload16(gWh + so + 2048, &sWh[ls + 2048]);
    gload16(gWl + so, &sWl[ls]);
    gload16(gWl + so + 2048, &sWl[ls + 2048]);
    __syncthreads();

    half8 ah[4], al[4], bh[4], bl[4];
#pragma unroll
    for (int i = 0; i < 4; ++i) {
      ah[i] = *(const half8*)&sAh[ra + i * 512];
      al[i] = *(const half8*)&sAl[ra + i * 512];
      bh[i] = *(const half8*)&sWh[rb + i * 512];
      bl[i] = *(const half8*)&sWl[rb + i * 512];
    }
#pragma unroll
    for (int a = 0; a < 4; ++a) {
#pragma unroll
      for (int b = 0; b < 4; ++b) {
        acc[a][b] = __builtin_amdgcn_mfma_f32_16x16x32_f16(ah[a], bh[b], acc[a][b], 0, 0, 0);
        acc[a][b] = __builtin_amdgcn_mfma_f32_16x16x32_f16(ah[a], bl[b], acc[a][b], 0, 0, 0);
        acc[a][b] = __builtin_amdgcn_mfma_f32_16x16x32_f16(al[a], bh[b], acc[a][b], 0, 0, 0);
      }
    }
  }

  // epilogue: C/D layout col=lane&15, row=quad*4+reg
  const int64_t m0 = (int64_t)mt * 128;
  const int64_t n0 = (int64_t)nt * 128;
#pragma unroll
  for (int a = 0; a < 4; ++a) {
#pragma unroll
    for (int r = 0; r < 4; ++r) {
      const int64_t row = m0 + wm + a * 16 + quad * 4 + r;
      float* dst = Hbuf + row * H_SZ + n0 + wn + fr;
#pragma unroll
      for (int b = 0; b < 4; ++b) dst[b * 16] = acc[a][b][r];
    }
  }
}

// ---------- BN stats: 64-wide coalesced column sums ----------
__global__ void k_stats(const float* __restrict__ Hbuf, const float* __restrict__ gamma,
                        float* __restrict__ scale, float* __restrict__ shift) {
  const int t = blockIdx.y;
  const int tx = threadIdx.x & 63;
  const int ty = threadIdx.x >> 6;  // 0..3
  const int h = blockIdx.x * 64 + tx;
  const float* p = Hbuf + ((int64_t)t * B_SZ + ty * 128) * H_SZ + h;
  float s = 0.f, s2 = 0.f;
#pragma unroll 8
  for (int i = 0; i < 128; ++i) {
    float v = p[(int64_t)i * H_SZ];
    s += v;
    s2 += v * v;
  }
  __shared__ float ss[4][64];
  __shared__ float sq[4][64];
  ss[ty][tx] = s;
  sq[ty][tx] = s2;
  __syncthreads();
  if (ty == 0) {
    float a = ss[0][tx] + ss[1][tx] + ss[2][tx] + ss[3][tx];
    float b = sq[0][tx] + sq[1][tx] + sq[2][tx] + sq[3][tx];
    const float mean = a * (1.0f / B_SZ);
    const float var = b * (1.0f / B_SZ) - mean * mean;
    const float rs = rsqrtf(var + 1e-4f);
    const float sc = gamma[t * H_SZ + h] * rs;
    scale[t * H_SZ + h] = sc;
    shift[t * H_SZ + h] = -mean * sc;
  }
}

// ---------- LIF recurrence per (b,h): spike count S ----------
__global__ void k_recur(const float* __restrict__ Hbuf, const float* __restrict__ scale,
                        const float* __restrict__ shift, _Float16* __restrict__ S) {
  const int idx = blockIdx.x * 256 + threadIdx.x;
  const int b = idx >> 10;
  const int h = idx & 1023;
  float mem = 0.f;
  int cnt = 0;
#pragma unroll
  for (int t = 0; t < T_STEPS; ++t) {
    float v = Hbuf[((int64_t)(t * B_SZ + b) << 10) + h];
    v = v * scale[(t << 10) + h] + shift[(t << 10) + h];
    mem = 0.95f * mem + v;
    if (mem - 1.0f > 0.0f) {
      ++cnt;
      mem -= 1.0f;
    }
  }
  S[idx] = (_Float16)cnt;
}

// ---------- GEMM2: out = S @ W2^T / 20, 2-term fp16 split (exact: S integer) ----------
__global__ void k_gemm2(const _Float16* __restrict__ S, const _Float16* __restrict__ W2h,
                        const _Float16* __restrict__ W2l, float* __restrict__ out) {
  const int wid = threadIdx.x >> 6;
  const int lane = threadIdx.x & 63;
  const int m0 = blockIdx.y * 64 + wid * 16;
  const int n0 = blockIdx.x * 16;
  const int fr = lane & 15;
  const int quad = lane >> 4;

  const _Float16* sp = S + (int64_t)(m0 + fr) * H_SZ + quad * 8;
  const _Float16* wph = W2h + (int64_t)(n0 + fr) * H_SZ + quad * 8;
  const _Float16* wpl = W2l + (int64_t)(n0 + fr) * H_SZ + quad * 8;

  f32x4 acc = {0.f, 0.f, 0.f, 0.f};
#pragma unroll 4
  for (int k = 0; k < H_SZ; k += 32) {
    half8 a = *(const half8*)(sp + k);
    half8 bh = *(const half8*)(wph + k);
    half8 bl = *(const half8*)(wpl + k);
    acc = __builtin_amdgcn_mfma_f32_16x16x32_f16(a, bh, acc, 0, 0, 0);
    acc = __builtin_amdgcn_mfma_f32_16x16x32_f16(a, bl, acc, 0, 0, 0);
  }
  const int col = n0 + fr;
  if (col < C_SZ) {
#pragma unroll
    for (int r = 0; r < 4; ++r) {
      const int row = m0 + quad * 4 + r;
      out[row * C_SZ + col] = acc[r] * (1.0f / T_STEPS);
    }
  }
}

extern "C" void kernel_launch(void* const* d_in, const int* in_sizes, int n_in,
                              void* d_out, int out_size, void* d_ws, size_t ws_size,
                              hipStream_t stream) {
  const float* z = (const float*)d_in[0];      // [20,512,4096]
  const float* W1 = (const float*)d_in[1];     // [1024,4096]
  const float* gamma = (const float*)d_in[2];  // [20,1024]
  const float* W2 = (const float*)d_in[3];     // [100,1024]
  float* out = (float*)d_out;                  // [512,100]

  char* ws = (char*)d_ws;
  size_t off = 0;
  auto alloc = [&](size_t bytes) -> void* {
    void* p = ws + off;
    off += (bytes + 255) & ~(size_t)255;
    return p;
  };
  _Float16* Azh = (_Float16*)alloc((size_t)M_TOT * D_IN * 2);
  _Float16* Azl = (_Float16*)alloc((size_t)M_TOT * D_IN * 2);
  _Float16* Wfh = (_Float16*)alloc((size_t)H_SZ * D_IN * 2);
  _Float16* Wfl = (_Float16*)alloc((size_t)H_SZ * D_IN * 2);
  float* Hbuf = (float*)alloc((size_t)M_TOT * H_SZ * 4);
  float* scale = (float*)alloc((size_t)T_STEPS * H_SZ * 4);
  float* shift = (float*)alloc((size_t)T_STEPS * H_SZ * 4);
  _Float16* S = (_Float16*)alloc((size_t)B_SZ * H_SZ * 2);
  _Float16* W2h = (_Float16*)alloc((size_t)112 * H_SZ * 2);
  _Float16* W2l = (_Float16*)alloc((size_t)112 * H_SZ * 2);

  // 1) z + W1 -> fragment-tiled fp16 hi/lo planes; W2 hi/lo
  dim3 gp(KITERS, 88);  // 80 z row-tiles + 8 W1 row-tiles
  k_prep_frag<<<gp, 256, 0, stream>>>(z, Azh, Azl, W1, Wfh, Wfl);
  k_prep_w2<<<(112 * H_SZ) / 256, 256, 0, stream>>>(W2, W2h, W2l);

  // 2) batched fc1 GEMM (R2 structure, conflict-free fragment-order LDS)
  k_gemm1<<<640, 256, 0, stream>>>(Azh, Azl, Wfh, Wfl, Hbuf);

  // 3) BN stats
  dim3 gs(H_SZ / 64, T_STEPS);  // (16, 20)
  k_stats<<<gs, 256, 0, stream>>>(Hbuf, gamma, scale, shift);

  // 4) LIF recurrence -> spike counts
  k_recur<<<(B_SZ * H_SZ) / 256, 256, 0, stream>>>(Hbuf, scale, shift, S);

  // 5) spike-count GEMM -> output
  dim3 g2(7, 8);
  k_gemm2<<<g2, 256, 0, stream>>>(S, W2h, W2l, out);
}